// Round 8
// baseline (542.464 us; speedup 1.0000x reference)
//
#include <hip/hip_runtime.h>
#include <math.h>

#define NBATCH 8
#define NPTS   1024
#define KNN    8
#define CC     128
#define HD_    128
#define TED_   128
#define TEC_   64
#define RH     32
#define NL     4

typedef _Float16 half8 __attribute__((ext_vector_type(8)));
typedef _Float16 h4v  __attribute__((ext_vector_type(4)));
typedef float f32x4 __attribute__((ext_vector_type(4)));

__device__ __forceinline__ unsigned long long shflxor_u64(unsigned long long v, int m) {
  return (unsigned long long)__shfl_xor((long long)v, m, 8);
}

// ---------------------------------------------------------------- temb
__global__ __launch_bounds__(128) void k_temb(
    const float* __restrict__ t, const float* __restrict__ Wt1,
    const float* __restrict__ bt1, const float* __restrict__ Wt2,
    const float* __restrict__ bt2, const float* __restrict__ Win0,
    const float* __restrict__ bin0, float* __restrict__ pre0)
{
  int b = blockIdx.x;
  int tid = threadIdx.x;
  __shared__ float e128[TED_];
  __shared__ float h1[TED_];
  __shared__ float te[TEC_];
  float tv = t[b];
  if (tid < 64) {
    float fr = expf((-9.210340371976184f * (float)tid) * 0.015625f);
    float em = tv * fr;
    e128[tid]      = sinf(em);
    e128[tid + 64] = cosf(em);
  }
  __syncthreads();
  {
    float acc = bt1[tid];
    for (int i = 0; i < TED_; ++i) acc += e128[i] * Wt1[i * TED_ + tid];
    h1[tid] = acc / (1.0f + expf(-acc));
  }
  __syncthreads();
  if (tid < TEC_) {
    float acc = bt2[tid];
    for (int j = 0; j < TED_; ++j) acc += h1[j] * Wt2[j * TEC_ + tid];
    te[tid] = acc;
  }
  __syncthreads();
  {
    float acc = bin0[tid];
    for (int i = 0; i < TEC_; ++i) acc += te[i] * Win0[i * CC + tid];
    pre0[b * CC + tid] = acc;
  }
}

// ---------------------------------------------------------------- init f0/f1 (+fp16 copies)
__global__ __launch_bounds__(256) void k_init(
    const float* __restrict__ x, const float* __restrict__ Win0,
    const float* __restrict__ Win1, const float* __restrict__ pre0,
    float* __restrict__ f0, float* __restrict__ f1,
    _Float16* __restrict__ f0h, _Float16* __restrict__ f1h)
{
  int node = blockIdx.x * 2 + (threadIdx.x >> 7);
  int c = threadIdx.x & 127;
  int b = node >> 10;
  float x0 = x[node * 3 + 0], x1 = x[node * 3 + 1], x2 = x[node * 3 + 2];
  float acc = pre0[b * CC + c]
            + x0 * Win0[(TEC_ + 0) * CC + c]
            + x1 * Win0[(TEC_ + 1) * CC + c]
            + x2 * Win0[(TEC_ + 2) * CC + c];
  f0[(size_t)node * CC + c] = acc;
  f0h[(size_t)node * CC + c] = (_Float16)acc;
  float w1 = Win1[c];
  float v0 = x0 * w1, v1 = x1 * w1, v2 = x2 * w1;
  f1[((size_t)node * 3 + 0) * CC + c] = v0;
  f1[((size_t)node * 3 + 1) * CC + c] = v1;
  f1[((size_t)node * 3 + 2) * CC + c] = v2;
  f1h[((size_t)node * 3 + 0) * CC + c] = (_Float16)v0;
  f1h[((size_t)node * 3 + 1) * CC + c] = (_Float16)v1;
  f1h[((size_t)node * 3 + 2) * CC + c] = (_Float16)v2;
}

// ---------------------------------------------------------------- knn v3
__global__ __launch_bounds__(256) void k_knn(
    const float* __restrict__ x, int* __restrict__ idx,
    float* __restrict__ rhat, float* __restrict__ rl)
{
  const int b    = blockIdx.x >> 5;
  const int tile = blockIdx.x & 31;
  const int tid  = threadIdx.x;
  const int qg   = tid >> 3;
  const int sub  = tid & 7;

  __shared__ float xsx[NPTS], xsy[NPTS], xsz[NPTS];

  for (int i = tid; i < NPTS; i += 256) {
    const float* xp = x + ((size_t)b * NPTS + i) * 3;
    xsx[i] = xp[0]; xsy[i] = xp[1]; xsz[i] = xp[2];
  }
  __syncthreads();

  const int n = tile * 32 + qg;
  const float qx = xsx[n], qy = xsy[n], qz = xsz[n];

  unsigned long long bd[KNN];
  #pragma unroll
  for (int k = 0; k < KNN; ++k) bd[k] = ~0ull;

  const int j0 = sub * 128;
  const int ph = sub * 4;
  for (int it = 0; it < 128; ++it) {
    int j = j0 + ((it + ph) & 127);
    float dx = qx - xsx[j];
    float dy = qy - xsy[j];
    float dz = qz - xsz[j];
    float s = __fadd_rn(__fadd_rn(__fmul_rn(dx, dx), __fmul_rn(dy, dy)),
                        __fmul_rn(dz, dz));
    if (j == n) s = 1.0e9f;
    unsigned long long key =
        ((unsigned long long)__float_as_uint(s) << 32) | (unsigned int)j;
    if (key < bd[KNN - 1]) {
      bd[KNN - 1] = key;
      #pragma unroll
      for (int q = KNN - 1; q > 0; --q) {
        if (bd[q] < bd[q - 1]) {
          unsigned long long tmp = bd[q]; bd[q] = bd[q - 1]; bd[q - 1] = tmp;
        }
      }
    }
  }

  unsigned long long res[KNN];
  #pragma unroll
  for (int r = 0; r < KNN; ++r) {
    unsigned long long m = bd[0];
    unsigned long long o;
    o = shflxor_u64(m, 1); m = (o < m) ? o : m;
    o = shflxor_u64(m, 2); m = (o < m) ? o : m;
    o = shflxor_u64(m, 4); m = (o < m) ? o : m;
    if (bd[0] == m) {
      #pragma unroll
      for (int q = 0; q < KNN - 1; ++q) bd[q] = bd[q + 1];
      bd[KNN - 1] = ~0ull;
    }
    res[r] = m;
  }

  unsigned long long key = res[0];
  #pragma unroll
  for (int r = 1; r < KNN; ++r) if (sub == r) key = res[r];
  int j = (int)(key & 0xffffffffu);
  size_t base = ((size_t)b * NPTS + n) * KNN + sub;
  idx[base] = j;
  float rx = xsx[j] - qx;
  float ry = xsy[j] - qy;
  float rz = xsz[j] - qz;
  float rr2 = rx * rx + ry * ry + rz * rz + 1e-8f;
  float r = sqrtf(rr2);
  rl[base] = r;
  rhat[base * 3 + 0] = rx / r;
  rhat[base * 3 + 1] = ry / r;
  rhat[base * 3 + 2] = rz / r;
}

// ---------------------------------------------------------------- Rn precompute (all layers, once)
// Rn[l][edge][h*16+j] fp16, edge = node*KNN+k, j<10
__global__ __launch_bounds__(256) void k_rn(
    const float* __restrict__ rl, const float* __restrict__ Wr1,
    const float* __restrict__ br1, const float* __restrict__ Wr2,
    const float* __restrict__ br2, _Float16* __restrict__ Rn)
{
  const int l = blockIdx.y;
  const int e0 = blockIdx.x * 64;
  const int t = threadIdx.x;
  __shared__ float rls[64];
  __shared__ float hid[64][33];
  __shared__ float wsm[RH * 80];
  if (t < 64) rls[t] = rl[e0 + t];
  {
    const float* wr2 = Wr2 + l * RH * 80;
    for (int i = t; i < RH * 80; i += 256) wsm[i] = wr2[i];
  }
  __syncthreads();
  {
    const float* wr1 = Wr1 + l * RH;
    const float* wb1 = br1 + l * RH;
    int e = t >> 2, ib = (t & 3) * 8;
    float rv = rls[e];
    #pragma unroll
    for (int q = 0; q < 8; ++q) {
      int i = ib + q;
      float zv = rv * wr1[i] + wb1[i];
      hid[e][i] = zv / (1.0f + expf(-zv));
    }
  }
  __syncthreads();
  {
    const float* wb2 = br2 + l * 80;
    int e = t >> 2, cg = t & 3;
    _Float16* dst = Rn + (((size_t)l * 65536) + e0 + e) * 128;
    #pragma unroll
    for (int q = 0; q < 20; ++q) {
      int col = cg * 20 + q;
      float acc = wb2[col];
      #pragma unroll
      for (int i = 0; i < RH; ++i) acc += hid[e][i] * wsm[i * 80 + col];
      int hh = col / 10, j = col - hh * 10;
      dst[hh * 16 + j] = (_Float16)acc;
    }
  }
}

// ---------------------------------------------------------------- W convert+transpose (once)
__global__ __launch_bounds__(256) void k_wconv(
    const float* __restrict__ Wqkv, const float* __restrict__ Wo,
    _Float16* __restrict__ Whq, _Float16* __restrict__ Who)
{
  __shared__ _Float16 T[128][136];
  int m = blockIdx.x;
  const float* src; _Float16* dst;
  if (m < 48) { src = Wqkv + (size_t)m * 16384; dst = Whq + (size_t)m * 16384; }
  else { src = Wo + (size_t)(m - 48) * 16384; dst = Who + (size_t)(m - 48) * 16384; }
  int tid = threadIdx.x;
  for (int i = tid; i < 16384; i += 256) {
    int k = i >> 7, n = i & 127;
    T[n][k] = (_Float16)src[i];
  }
  __syncthreads();
  for (int i = tid; i < 16384; i += 256) {
    int n = i >> 7, k = i & 127;
    dst[i] = T[n][k];
  }
}

// ---------------------------------------------------------------- MFMA tile body (128x128x128)
#define MFMA_BODY(A_, ROWBASE_, WT_)                                          \
  const int tid  = threadIdx.x;                                               \
  const int lane = tid & 63;                                                  \
  const int w    = tid >> 6;                                                  \
  const int r15  = lane & 15;                                                 \
  const int g    = lane >> 4;                                                 \
  half8 bf[2][4];                                                             \
  _Pragma("unroll")                                                           \
  for (int ntl = 0; ntl < 2; ++ntl) {                                         \
    int n = (w * 2 + ntl) * 16 + r15;                                         \
    const _Float16* wp = (WT_) + (size_t)n * 128 + g * 8;                     \
    _Pragma("unroll")                                                         \
    for (int ks = 0; ks < 4; ++ks)                                            \
      bf[ntl][ks] = *(const half8*)(wp + ks * 32);                            \
  }                                                                           \
  {                                                                           \
    int r = tid >> 1;                                                         \
    const _Float16* src = (A_) + (size_t)((ROWBASE_) + r) * 128;              \
    int c0 = (tid & 1) * 8;                                                   \
    _Pragma("unroll")                                                         \
    for (int q = 0; q < 8; ++q) {                                             \
      int c = c0 + q;                                                         \
      *(uint4*)&As[r][c * 8] = *(const uint4*)(src + c * 8);                  \
    }                                                                         \
  }                                                                           \
  __syncthreads();                                                            \
  f32x4 acc[8][2] = {};                                                       \
  _Pragma("unroll")                                                           \
  for (int ks = 0; ks < 4; ++ks) {                                            \
    half8 a[8];                                                               \
    _Pragma("unroll")                                                         \
    for (int mt = 0; mt < 8; ++mt)                                            \
      a[mt] = *(const half8*)&As[mt * 16 + r15][ks * 32 + g * 8];             \
    _Pragma("unroll")                                                         \
    for (int mt = 0; mt < 8; ++mt) {                                          \
      acc[mt][0] = __builtin_amdgcn_mfma_f32_16x16x32_f16(a[mt], bf[0][ks], acc[mt][0], 0, 0, 0); \
      acc[mt][1] = __builtin_amdgcn_mfma_f32_16x16x32_f16(a[mt], bf[1][ks], acc[mt][1], 0, 0, 0); \
    }                                                                         \
  }

// ---------------------------------------------------------------- proj MFMA
__global__ __launch_bounds__(256) void k_proj_mfma(
    const _Float16* __restrict__ f0h, const _Float16* __restrict__ f1h,
    const _Float16* __restrict__ Wh, _Float16* __restrict__ P0,
    _Float16* __restrict__ P1, int nb0)
{
  __shared__ _Float16 As[128][136];
  int z = blockIdx.x;
  const _Float16* A; const _Float16* Wt; _Float16* P; int ldP, colBase, rowBase;
  if (z < nb0 * 5) {
    const int map0[5] = {0, 2, 4, 7, 9};
    int m = z / nb0, rb = z - m * nb0;
    A = f0h; rowBase = rb * 128;
    Wt = Wh + (size_t)map0[m] * 16384;
    P = P0; ldP = 640; colBase = m * 128;
  } else {
    z -= nb0 * 5;
    int nb1 = nb0 * 3;
    const int map1[7] = {1, 3, 5, 6, 8, 10, 11};
    int m = z / nb1, rb = z - m * nb1;
    A = f1h; rowBase = rb * 128;
    Wt = Wh + (size_t)map1[m] * 16384;
    P = P1; ldP = 896; colBase = m * 128;
  }
  MFMA_BODY(A, rowBase, Wt)
  #pragma unroll
  for (int mt = 0; mt < 8; ++mt) {
    #pragma unroll
    for (int ntl = 0; ntl < 2; ++ntl) {
      int col = colBase + (w * 2 + ntl) * 16 + r15;
      #pragma unroll
      for (int i = 0; i < 4; ++i) {
        int r = rowBase + mt * 16 + g * 4 + i;
        P[(size_t)r * ldP + col] = (_Float16)acc[mt][ntl][i];
      }
    }
  }
}

// ---------------------------------------------------------------- Wo MFMA + residual
__global__ __launch_bounds__(256) void k_wo_mfma(
    const _Float16* __restrict__ o0h, const _Float16* __restrict__ o1h,
    const _Float16* __restrict__ Who_l, const float* __restrict__ bo_l,
    float* __restrict__ f0, float* __restrict__ f1,
    _Float16* __restrict__ f0h, _Float16* __restrict__ f1h, int nb0)
{
  __shared__ _Float16 As[128][136];
  int z = blockIdx.x;
  const _Float16* A; const _Float16* Wt; const float* bias;
  float* F; _Float16* FH; int rowBase;
  if (z < nb0) {
    A = o0h; Wt = Who_l; bias = bo_l; F = f0; FH = f0h; rowBase = z * 128;
  } else {
    z -= nb0;
    A = o1h; Wt = Who_l + 16384; bias = bo_l + CC; F = f1; FH = f1h; rowBase = z * 128;
  }
  MFMA_BODY(A, rowBase, Wt)
  #pragma unroll
  for (int mt = 0; mt < 8; ++mt) {
    #pragma unroll
    for (int ntl = 0; ntl < 2; ++ntl) {
      int col = (w * 2 + ntl) * 16 + r15;
      float bv = bias[col];
      #pragma unroll
      for (int i = 0; i < 4; ++i) {
        int r = rowBase + mt * 16 + g * 4 + i;
        size_t p = (size_t)r * 128 + col;
        float val = F[p] + acc[mt][ntl][i] + bv;
        F[p] = val;
        FH[p] = (_Float16)val;
      }
    }
  }
}

// ---------------------------------------------------------------- attn v5
// 64 lanes per node: 32 channel-groups x 2 neighbor-halves (4 neighbors each),
// online softmax per half + shuffle merge. Rn precomputed. 4 nodes/block.
__global__ __launch_bounds__(256) void k_attn(
    const _Float16* __restrict__ P0, const _Float16* __restrict__ P1,
    const int* __restrict__ idx, const float* __restrict__ rhat,
    const _Float16* __restrict__ RnL,
    _Float16* __restrict__ o0h, _Float16* __restrict__ o1h,
    int nodeBase, int nbg)
{
  const int t = threadIdx.x;
  const int wv = t >> 6;            // node slot 0..3
  const int lane = t & 63;
  const int cl = lane & 31;         // channel group
  const int nh = lane >> 5;         // neighbor half
  const int z = blockIdx.x;
  const int bb = z % nbg;
  const int qbase = (z / nbg) * 4;
  const int nodeLocal = bb * NPTS + qbase + wv;
  const int node = nodeBase + nodeLocal;
  const int batchRow = bb * NPTS;

  __shared__ float rh_s[4][KNN][3];
  if (t < 96) {
    int nd = t / 24, e = t % 24;
    rh_s[nd][e / 3][e % 3] =
        rhat[((size_t)(nodeBase + bb * NPTS + qbase + nd)) * KNN * 3 + e];
  }
  __syncthreads();

  const int c0 = cl * 4;
  const int h = cl >> 2;
  const _Float16* p0n = P0 + (size_t)nodeLocal * 640 + c0;
  const _Float16* p1n = P1 + (size_t)nodeLocal * 2688 + c0;
  h4v q0v  = *(const h4v*)(p0n);
  h4v q1xv = *(const h4v*)(p1n);
  h4v q1yv = *(const h4v*)(p1n + 896);
  h4v q1zv = *(const h4v*)(p1n + 1792);

  const float inv_scale = 0.17677669529663687f;  // 1/sqrt(32)
  const int* idxp = idx + (size_t)node * KNN + nh * 4;
  int jls[4];
  #pragma unroll
  for (int k = 0; k < 4; ++k) jls[k] = batchRow + idxp[k];
  const _Float16* rnp = RnL + ((size_t)node * KNN + nh * 4) * 128 + h * 16;

  float m = -3.0e38f, ssum = 0.0f;
  float a0[4] = {}, ax[4] = {}, ay[4] = {}, az[4] = {};

  for (int k = 0; k < 4; ++k) {
    int kk = nh * 4 + k;
    int jl = jls[k];
    const _Float16* g0 = P0 + (size_t)jl * 640 + c0;
    const _Float16* g1 = P1 + (size_t)jl * 2688 + c0;
    float rx = rh_s[wv][kk][0], ry = rh_s[wv][kk][1], rz = rh_s[wv][kk][2];

    h4v G02 = *(const h4v*)(g0 + 128), G04 = *(const h4v*)(g0 + 256);
    h4v G07 = *(const h4v*)(g0 + 384), G09 = *(const h4v*)(g0 + 512);
    h4v G13x = *(const h4v*)(g1 + 128),  G13y = *(const h4v*)(g1 + 896 + 128),  G13z = *(const h4v*)(g1 + 1792 + 128);
    h4v G15x = *(const h4v*)(g1 + 256),  G15y = *(const h4v*)(g1 + 896 + 256),  G15z = *(const h4v*)(g1 + 1792 + 256);
    h4v G16x = *(const h4v*)(g1 + 384),  G16y = *(const h4v*)(g1 + 896 + 384),  G16z = *(const h4v*)(g1 + 1792 + 384);
    h4v G18x = *(const h4v*)(g1 + 512),  G18y = *(const h4v*)(g1 + 896 + 512),  G18z = *(const h4v*)(g1 + 1792 + 512);
    h4v G1Ax = *(const h4v*)(g1 + 640),  G1Ay = *(const h4v*)(g1 + 896 + 640),  G1Az = *(const h4v*)(g1 + 1792 + 640);
    h4v G1Bx = *(const h4v*)(g1 + 768),  G1By = *(const h4v*)(g1 + 896 + 768),  G1Bz = *(const h4v*)(g1 + 1792 + 768);

    half8 rv = *(const half8*)(rnp + (size_t)k * 128);
    h4v rv2 = *(const h4v*)(rnp + (size_t)k * 128 + 8);
    float r0 = (float)rv[0], r1 = (float)rv[1], r2 = (float)rv[2], r3 = (float)rv[3];
    float r4 = (float)rv[4], r5 = (float)rv[5], r6 = (float)rv[6], r7 = (float)rv[7];
    float r8 = (float)rv2[0], r9 = (float)rv2[1];

    float pl = 0.0f;
    float v0c[4], vxc[4], vyc[4], vzc[4];
    #pragma unroll
    for (int ci = 0; ci < 4; ++ci) {
      float g02 = (float)G02[ci], g04 = (float)G04[ci];
      float g07 = (float)G07[ci], g09 = (float)G09[ci];
      float g13x = (float)G13x[ci], g13y = (float)G13y[ci], g13z = (float)G13z[ci];
      float g15x = (float)G15x[ci], g15y = (float)G15y[ci], g15z = (float)G15z[ci];
      float g16x = (float)G16x[ci], g16y = (float)G16y[ci], g16z = (float)G16z[ci];
      float g18x = (float)G18x[ci], g18y = (float)G18y[ci], g18z = (float)G18z[ci];
      float g1ax = (float)G1Ax[ci], g1ay = (float)G1Ay[ci], g1az = (float)G1Az[ci];
      float g1bx = (float)G1Bx[ci], g1by = (float)G1By[ci], g1bz = (float)G1Bz[ci];

      float DP3 = g13x * rx + g13y * ry + g13z * rz;
      float DP6 = g16x * rx + g16y * ry + g16z * rz;
      float DP8 = g18x * rx + g18y * ry + g18z * rz;
      float DPB = g1bx * rx + g1by * ry + g1bz * rz;

      float k0  = g02 * r0 + DP3 * r1;
      float k1x = g04 * rx * r2 + g15x * r3 + (3.0f * rx * DP6 - g16x) * r4;
      float k1y = g04 * ry * r2 + g15y * r3 + (3.0f * ry * DP6 - g16y) * r4;
      float k1z = g04 * rz * r2 + g15z * r3 + (3.0f * rz * DP6 - g16z) * r4;
      v0c[ci] = g07 * r5 + DP8 * r6;
      vxc[ci] = g09 * rx * r7 + g1ax * r8 + (3.0f * rx * DPB - g1bx) * r9;
      vyc[ci] = g09 * ry * r7 + g1ay * r8 + (3.0f * ry * DPB - g1by) * r9;
      vzc[ci] = g09 * rz * r7 + g1az * r8 + (3.0f * rz * DPB - g1bz) * r9;

      pl += (float)q0v[ci] * k0 + (float)q1xv[ci] * k1x
          + (float)q1yv[ci] * k1y + (float)q1zv[ci] * k1z;
    }
    pl += __shfl_xor(pl, 1, 4);
    pl += __shfl_xor(pl, 2, 4);
    pl *= inv_scale;

    float mnew = fmaxf(m, pl);
    float scale = expf(m - mnew);
    float wgt = expf(pl - mnew);
    ssum = ssum * scale + wgt;
    #pragma unroll
    for (int ci = 0; ci < 4; ++ci) {
      a0[ci] = a0[ci] * scale + wgt * v0c[ci];
      ax[ci] = ax[ci] * scale + wgt * vxc[ci];
      ay[ci] = ay[ci] * scale + wgt * vyc[ci];
      az[ci] = az[ci] * scale + wgt * vzc[ci];
    }
    m = mnew;
  }

  // merge the two neighbor-halves (lane ^ 32)
  {
    float mo = __shfl_xor(m, 32, 64);
    float so = __shfl_xor(ssum, 32, 64);
    float mn = fmaxf(m, mo);
    float s_self = expf(m - mn);
    float s_oth  = expf(mo - mn);
    ssum = ssum * s_self + so * s_oth;
    #pragma unroll
    for (int ci = 0; ci < 4; ++ci) {
      float o0 = __shfl_xor(a0[ci], 32, 64);
      float ox = __shfl_xor(ax[ci], 32, 64);
      float oy = __shfl_xor(ay[ci], 32, 64);
      float oz = __shfl_xor(az[ci], 32, 64);
      a0[ci] = a0[ci] * s_self + o0 * s_oth;
      ax[ci] = ax[ci] * s_self + ox * s_oth;
      ay[ci] = ay[ci] * s_self + oy * s_oth;
      az[ci] = az[ci] * s_self + oz * s_oth;
    }
  }

  if (nh == 0) {
    float invs = 1.0f / ssum;
    h4v o;
    #pragma unroll
    for (int ci = 0; ci < 4; ++ci) o[ci] = (_Float16)(a0[ci] * invs);
    *(h4v*)(o0h + (size_t)nodeLocal * 128 + c0) = o;
    #pragma unroll
    for (int ci = 0; ci < 4; ++ci) o[ci] = (_Float16)(ax[ci] * invs);
    *(h4v*)(o1h + ((size_t)nodeLocal * 3 + 0) * 128 + c0) = o;
    #pragma unroll
    for (int ci = 0; ci < 4; ++ci) o[ci] = (_Float16)(ay[ci] * invs);
    *(h4v*)(o1h + ((size_t)nodeLocal * 3 + 1) * 128 + c0) = o;
    #pragma unroll
    for (int ci = 0; ci < 4; ++ci) o[ci] = (_Float16)(az[ci] * invs);
    *(h4v*)(o1h + ((size_t)nodeLocal * 3 + 2) * 128 + c0) = o;
  }
}

// ---------------------------------------------------------------- final out
__global__ __launch_bounds__(256) void k_out(
    const float* __restrict__ f1, const float* __restrict__ Wout,
    const float* __restrict__ bout, float* __restrict__ out)
{
  int i = blockIdx.x * 256 + threadIdx.x;
  int v = i % 3;
  const float* row = f1 + (size_t)i * CC;
  const float* w = Wout + v * CC;
  float acc = 0.0f;
  #pragma unroll
  for (int c = 0; c < CC; c += 4) {
    float4 fv = *(const float4*)&row[c];
    float4 wv = *(const float4*)&w[c];
    acc += fv.x * wv.x + fv.y * wv.y + fv.z * wv.z + fv.w * wv.w;
  }
  out[i] = acc + bout[v];
}

// ---------------------------------------------------------------- host
extern "C" void kernel_launch(void* const* d_in, const int* in_sizes, int n_in,
                              void* d_out, int out_size, void* d_ws, size_t ws_size,
                              hipStream_t stream) {
  const float* x    = (const float*)d_in[0];
  const float* t    = (const float*)d_in[2];
  const float* Wt1  = (const float*)d_in[3];
  const float* bt1  = (const float*)d_in[4];
  const float* Wt2  = (const float*)d_in[5];
  const float* bt2  = (const float*)d_in[6];
  const float* Win0 = (const float*)d_in[7];
  const float* bin0 = (const float*)d_in[8];
  const float* Win1 = (const float*)d_in[9];
  const float* Wqkv = (const float*)d_in[10];
  const float* Wr1  = (const float*)d_in[11];
  const float* br1  = (const float*)d_in[12];
  const float* Wr2  = (const float*)d_in[13];
  const float* br2  = (const float*)d_in[14];
  const float* Wo   = (const float*)d_in[15];
  const float* bo   = (const float*)d_in[16];
  const float* Wout = (const float*)d_in[17];
  const float* bout = (const float*)d_in[18];
  float* out = (float*)d_out;

  char* wsb = (char*)d_ws;
  size_t off = 0;
  auto alloc = [&](size_t bytes) -> void* {
    void* p = wsb + off;
    off = (off + bytes + 255) & ~(size_t)255;
    return p;
  };
  const int totalNodes = NBATCH * NPTS;  // 8192
  float* pre0 = (float*)alloc((size_t)NBATCH * CC * 4);
  float* f0   = (float*)alloc((size_t)totalNodes * CC * 4);
  float* f1   = (float*)alloc((size_t)totalNodes * 3 * CC * 4);
  _Float16* f0h = (_Float16*)alloc((size_t)totalNodes * CC * 2);
  _Float16* f1h = (_Float16*)alloc((size_t)totalNodes * 3 * CC * 2);
  _Float16* Whq = (_Float16*)alloc((size_t)NL * 12 * CC * HD_ * 2);
  _Float16* Who = (_Float16*)alloc((size_t)NL * 2 * CC * HD_ * 2);
  int*   idx  = (int*)alloc((size_t)totalNodes * KNN * 4);
  float* rhat = (float*)alloc((size_t)totalNodes * KNN * 3 * 4);
  float* rl   = (float*)alloc((size_t)totalNodes * KNN * 4);
  _Float16* Rn = (_Float16*)alloc((size_t)NL * totalNodes * KNN * 128 * 2);
  size_t fixedBytes = off;
  size_t perBatch = (size_t)NPTS * ((640 + 2688) * 2 + (128 + 384) * 2);
  int nbg = 8;
  while (nbg > 1 && fixedBytes + (size_t)nbg * perBatch + 8192 > ws_size) nbg >>= 1;
  _Float16* P0  = (_Float16*)alloc((size_t)nbg * NPTS * 640 * 2);
  _Float16* P1  = (_Float16*)alloc((size_t)nbg * NPTS * 2688 * 2);
  _Float16* o0h = (_Float16*)alloc((size_t)nbg * NPTS * 128 * 2);
  _Float16* o1h = (_Float16*)alloc((size_t)nbg * NPTS * 384 * 2);

  k_temb<<<NBATCH, 128, 0, stream>>>(t, Wt1, bt1, Wt2, bt2, Win0, bin0, pre0);
  k_init<<<totalNodes / 2, 256, 0, stream>>>(x, Win0, Win1, pre0, f0, f1, f0h, f1h);
  k_knn<<<NBATCH * 32, 256, 0, stream>>>(x, idx, rhat, rl);
  k_wconv<<<56, 256, 0, stream>>>(Wqkv, Wo, Whq, Who);
  k_rn<<<dim3(totalNodes * KNN / 64, NL), 256, 0, stream>>>(rl, Wr1, br1, Wr2, br2, Rn);

  for (int g = 0; g < NBATCH / nbg; ++g) {
    int nodeBase = g * nbg * NPTS;
    int nodes = nbg * NPTS;
    int nb0 = nodes / 128;
    for (int l = 0; l < NL; ++l) {
      k_proj_mfma<<<nb0 * 26, 256, 0, stream>>>(
          f0h + (size_t)nodeBase * CC, f1h + (size_t)nodeBase * 3 * CC,
          Whq + (size_t)l * 12 * CC * HD_, P0, P1, nb0);
      k_attn<<<nodes / 4, 256, 0, stream>>>(
          P0, P1, idx, rhat, Rn + (size_t)l * totalNodes * KNN * 128,
          o0h, o1h, nodeBase, nbg);
      k_wo_mfma<<<nb0 * 4, 256, 0, stream>>>(
          o0h, o1h, Who + (size_t)l * 2 * CC * HD_, bo + (size_t)(l * 2) * CC,
          f0 + (size_t)nodeBase * CC, f1 + (size_t)nodeBase * 3 * CC,
          f0h + (size_t)nodeBase * CC, f1h + (size_t)nodeBase * 3 * CC, nb0);
    }
  }
  k_out<<<(totalNodes * 3) / 256, 256, 0, stream>>>(f1, Wout, bout, out);
}

// Round 9
// 416.793 us; speedup vs baseline: 1.3015x; 1.3015x over previous
//
#include <hip/hip_runtime.h>
#include <math.h>

#define NBATCH 8
#define NPTS   1024
#define KNN    8
#define CC     128
#define HD_    128
#define TED_   128
#define TEC_   64
#define RH     32
#define NL     4

typedef _Float16 half8 __attribute__((ext_vector_type(8)));
typedef _Float16 h4v  __attribute__((ext_vector_type(4)));
typedef float f32x4 __attribute__((ext_vector_type(4)));

__device__ __forceinline__ unsigned long long shflxor_u64(unsigned long long v, int m) {
  return (unsigned long long)__shfl_xor((long long)v, m, 8);
}

// ---------------------------------------------------------------- temb
__global__ __launch_bounds__(128) void k_temb(
    const float* __restrict__ t, const float* __restrict__ Wt1,
    const float* __restrict__ bt1, const float* __restrict__ Wt2,
    const float* __restrict__ bt2, const float* __restrict__ Win0,
    const float* __restrict__ bin0, float* __restrict__ pre0)
{
  int b = blockIdx.x;
  int tid = threadIdx.x;
  __shared__ float e128[TED_];
  __shared__ float h1[TED_];
  __shared__ float te[TEC_];
  float tv = t[b];
  if (tid < 64) {
    float fr = expf((-9.210340371976184f * (float)tid) * 0.015625f);
    float em = tv * fr;
    e128[tid]      = sinf(em);
    e128[tid + 64] = cosf(em);
  }
  __syncthreads();
  {
    float acc = bt1[tid];
    for (int i = 0; i < TED_; ++i) acc += e128[i] * Wt1[i * TED_ + tid];
    h1[tid] = acc / (1.0f + expf(-acc));
  }
  __syncthreads();
  if (tid < TEC_) {
    float acc = bt2[tid];
    for (int j = 0; j < TED_; ++j) acc += h1[j] * Wt2[j * TEC_ + tid];
    te[tid] = acc;
  }
  __syncthreads();
  {
    float acc = bin0[tid];
    for (int i = 0; i < TEC_; ++i) acc += te[i] * Win0[i * CC + tid];
    pre0[b * CC + tid] = acc;
  }
}

// ---------------------------------------------------------------- init f0/f1 (+fp16 copies)
__global__ __launch_bounds__(256) void k_init(
    const float* __restrict__ x, const float* __restrict__ Win0,
    const float* __restrict__ Win1, const float* __restrict__ pre0,
    float* __restrict__ f0, float* __restrict__ f1,
    _Float16* __restrict__ f0h, _Float16* __restrict__ f1h)
{
  int node = blockIdx.x * 2 + (threadIdx.x >> 7);
  int c = threadIdx.x & 127;
  int b = node >> 10;
  float x0 = x[node * 3 + 0], x1 = x[node * 3 + 1], x2 = x[node * 3 + 2];
  float acc = pre0[b * CC + c]
            + x0 * Win0[(TEC_ + 0) * CC + c]
            + x1 * Win0[(TEC_ + 1) * CC + c]
            + x2 * Win0[(TEC_ + 2) * CC + c];
  f0[(size_t)node * CC + c] = acc;
  f0h[(size_t)node * CC + c] = (_Float16)acc;
  float w1 = Win1[c];
  float v0 = x0 * w1, v1 = x1 * w1, v2 = x2 * w1;
  f1[((size_t)node * 3 + 0) * CC + c] = v0;
  f1[((size_t)node * 3 + 1) * CC + c] = v1;
  f1[((size_t)node * 3 + 2) * CC + c] = v2;
  f1h[((size_t)node * 3 + 0) * CC + c] = (_Float16)v0;
  f1h[((size_t)node * 3 + 1) * CC + c] = (_Float16)v1;
  f1h[((size_t)node * 3 + 2) * CC + c] = (_Float16)v2;
}

// ---------------------------------------------------------------- knn v3
__global__ __launch_bounds__(256) void k_knn(
    const float* __restrict__ x, int* __restrict__ idx,
    float* __restrict__ rhat, float* __restrict__ rl)
{
  const int b    = blockIdx.x >> 5;
  const int tile = blockIdx.x & 31;
  const int tid  = threadIdx.x;
  const int qg   = tid >> 3;
  const int sub  = tid & 7;

  __shared__ float xsx[NPTS], xsy[NPTS], xsz[NPTS];

  for (int i = tid; i < NPTS; i += 256) {
    const float* xp = x + ((size_t)b * NPTS + i) * 3;
    xsx[i] = xp[0]; xsy[i] = xp[1]; xsz[i] = xp[2];
  }
  __syncthreads();

  const int n = tile * 32 + qg;
  const float qx = xsx[n], qy = xsy[n], qz = xsz[n];

  unsigned long long bd[KNN];
  #pragma unroll
  for (int k = 0; k < KNN; ++k) bd[k] = ~0ull;

  const int j0 = sub * 128;
  const int ph = sub * 4;
  for (int it = 0; it < 128; ++it) {
    int j = j0 + ((it + ph) & 127);
    float dx = qx - xsx[j];
    float dy = qy - xsy[j];
    float dz = qz - xsz[j];
    float s = __fadd_rn(__fadd_rn(__fmul_rn(dx, dx), __fmul_rn(dy, dy)),
                        __fmul_rn(dz, dz));
    if (j == n) s = 1.0e9f;
    unsigned long long key =
        ((unsigned long long)__float_as_uint(s) << 32) | (unsigned int)j;
    if (key < bd[KNN - 1]) {
      bd[KNN - 1] = key;
      #pragma unroll
      for (int q = KNN - 1; q > 0; --q) {
        if (bd[q] < bd[q - 1]) {
          unsigned long long tmp = bd[q]; bd[q] = bd[q - 1]; bd[q - 1] = tmp;
        }
      }
    }
  }

  unsigned long long res[KNN];
  #pragma unroll
  for (int r = 0; r < KNN; ++r) {
    unsigned long long m = bd[0];
    unsigned long long o;
    o = shflxor_u64(m, 1); m = (o < m) ? o : m;
    o = shflxor_u64(m, 2); m = (o < m) ? o : m;
    o = shflxor_u64(m, 4); m = (o < m) ? o : m;
    if (bd[0] == m) {
      #pragma unroll
      for (int q = 0; q < KNN - 1; ++q) bd[q] = bd[q + 1];
      bd[KNN - 1] = ~0ull;
    }
    res[r] = m;
  }

  unsigned long long key = res[0];
  #pragma unroll
  for (int r = 1; r < KNN; ++r) if (sub == r) key = res[r];
  int j = (int)(key & 0xffffffffu);
  size_t base = ((size_t)b * NPTS + n) * KNN + sub;
  idx[base] = j;
  float rx = xsx[j] - qx;
  float ry = xsy[j] - qy;
  float rz = xsz[j] - qz;
  float rr2 = rx * rx + ry * ry + rz * rz + 1e-8f;
  float r = sqrtf(rr2);
  rl[base] = r;
  rhat[base * 3 + 0] = rx / r;
  rhat[base * 3 + 1] = ry / r;
  rhat[base * 3 + 2] = rz / r;
}

// ---------------------------------------------------------------- Rn precompute v2 (MFMA GEMM)
// Per block: 64 edges. Rn[e][col] = silu(rl[e]*Wr1+br1) @ Wr2 + br2,
// computed as [64x32]@[32x80] via mfma_f32_16x16x32_f16 (1 MFMA/wave/ntile).
// Output staged in LDS (scatter to padded h*16+j layout) then coalesced copy.
__global__ __launch_bounds__(256) void k_rn(
    const float* __restrict__ rl, const float* __restrict__ Wr1,
    const float* __restrict__ br1, const float* __restrict__ Wr2,
    const float* __restrict__ br2, _Float16* __restrict__ Rn)
{
  const int l = blockIdx.y;
  const int e0 = blockIdx.x * 64;
  const int t = threadIdx.x;
  __shared__ _Float16 hid[64][48];     // 96B rows (16B-aligned b128 reads)
  __shared__ _Float16 wt[80][48];      // Wr2^T fp16, 96B rows
  __shared__ _Float16 rn_lds[64][128];

  // zero output staging (pad slots must be deterministic)
  {
    uint4 zz = {0, 0, 0, 0};
    #pragma unroll
    for (int u = 0; u < 4; ++u)
      *(uint4*)((char*)rn_lds + (u * 256 + t) * 16) = zz;
  }
  // stage Wr2^T fp16: wt[n][k]
  {
    const float* wr2 = Wr2 + l * RH * 80;
    for (int i = t; i < 2560; i += 256) {
      int n = i >> 5, k = i & 31;
      wt[n][k] = (_Float16)wr2[k * 80 + n];
    }
  }
  // hid[e][i] = silu(rl[e]*Wr1[i]+br1[i]) in fp16
  {
    const float* wr1 = Wr1 + l * RH;
    const float* wb1 = br1 + l * RH;
    int e = t >> 2, i0 = (t & 3) * 8;
    float rv = rl[e0 + e];
    #pragma unroll
    for (int q = 0; q < 8; ++q) {
      int i = i0 + q;
      float zv = rv * wr1[i] + wb1[i];
      hid[e][i] = (_Float16)(zv / (1.0f + expf(-zv)));
    }
  }
  __syncthreads();

  // each wave: 16 edges x 80 cols = 5 MFMAs
  {
    const int lane = t & 63;
    const int w = t >> 6;
    const int r15 = lane & 15;
    const int g = lane >> 4;
    half8 af = *(const half8*)&hid[w * 16 + r15][g * 8];
    const float* wb2 = br2 + l * 80;
    #pragma unroll
    for (int nt = 0; nt < 5; ++nt) {
      half8 bf = *(const half8*)&wt[nt * 16 + r15][g * 8];
      f32x4 acc = {};
      acc = __builtin_amdgcn_mfma_f32_16x16x32_f16(af, bf, acc, 0, 0, 0);
      int col = nt * 16 + r15;
      int hh = col / 10, j = col - hh * 10;
      float bv = wb2[col];
      #pragma unroll
      for (int i = 0; i < 4; ++i) {
        int e = w * 16 + g * 4 + i;
        rn_lds[e][hh * 16 + j] = (_Float16)(acc[i] + bv);
      }
    }
  }
  __syncthreads();
  // coalesced 16B copy out
  _Float16* dst = Rn + ((size_t)l * 65536 + e0) * 128;
  #pragma unroll
  for (int u = 0; u < 4; ++u) {
    int i = u * 256 + t;
    *(uint4*)(dst + i * 8) = *(const uint4*)((const char*)rn_lds + i * 16);
  }
}

// ---------------------------------------------------------------- W convert+transpose (once)
__global__ __launch_bounds__(256) void k_wconv(
    const float* __restrict__ Wqkv, const float* __restrict__ Wo,
    _Float16* __restrict__ Whq, _Float16* __restrict__ Who)
{
  __shared__ _Float16 T[128][136];
  int m = blockIdx.x;
  const float* src; _Float16* dst;
  if (m < 48) { src = Wqkv + (size_t)m * 16384; dst = Whq + (size_t)m * 16384; }
  else { src = Wo + (size_t)(m - 48) * 16384; dst = Who + (size_t)(m - 48) * 16384; }
  int tid = threadIdx.x;
  for (int i = tid; i < 16384; i += 256) {
    int k = i >> 7, n = i & 127;
    T[n][k] = (_Float16)src[i];
  }
  __syncthreads();
  for (int i = tid; i < 16384; i += 256) {
    int n = i >> 7, k = i & 127;
    dst[i] = T[n][k];
  }
}

// ---------------------------------------------------------------- MFMA tile body (128x128x128)
#define MFMA_BODY(A_, ROWBASE_, WT_)                                          \
  const int tid  = threadIdx.x;                                               \
  const int lane = tid & 63;                                                  \
  const int w    = tid >> 6;                                                  \
  const int r15  = lane & 15;                                                 \
  const int g    = lane >> 4;                                                 \
  half8 bf[2][4];                                                             \
  _Pragma("unroll")                                                           \
  for (int ntl = 0; ntl < 2; ++ntl) {                                         \
    int n = (w * 2 + ntl) * 16 + r15;                                         \
    const _Float16* wp = (WT_) + (size_t)n * 128 + g * 8;                     \
    _Pragma("unroll")                                                         \
    for (int ks = 0; ks < 4; ++ks)                                            \
      bf[ntl][ks] = *(const half8*)(wp + ks * 32);                            \
  }                                                                           \
  {                                                                           \
    int r = tid >> 1;                                                         \
    const _Float16* src = (A_) + (size_t)((ROWBASE_) + r) * 128;              \
    int c0 = (tid & 1) * 8;                                                   \
    _Pragma("unroll")                                                         \
    for (int q = 0; q < 8; ++q) {                                             \
      int c = c0 + q;                                                         \
      *(uint4*)&As[r][c * 8] = *(const uint4*)(src + c * 8);                  \
    }                                                                         \
  }                                                                           \
  __syncthreads();                                                            \
  f32x4 acc[8][2] = {};                                                       \
  _Pragma("unroll")                                                           \
  for (int ks = 0; ks < 4; ++ks) {                                            \
    half8 a[8];                                                               \
    _Pragma("unroll")                                                         \
    for (int mt = 0; mt < 8; ++mt)                                            \
      a[mt] = *(const half8*)&As[mt * 16 + r15][ks * 32 + g * 8];             \
    _Pragma("unroll")                                                         \
    for (int mt = 0; mt < 8; ++mt) {                                          \
      acc[mt][0] = __builtin_amdgcn_mfma_f32_16x16x32_f16(a[mt], bf[0][ks], acc[mt][0], 0, 0, 0); \
      acc[mt][1] = __builtin_amdgcn_mfma_f32_16x16x32_f16(a[mt], bf[1][ks], acc[mt][1], 0, 0, 0); \
    }                                                                         \
  }

// ---------------------------------------------------------------- proj MFMA
__global__ __launch_bounds__(256) void k_proj_mfma(
    const _Float16* __restrict__ f0h, const _Float16* __restrict__ f1h,
    const _Float16* __restrict__ Wh, _Float16* __restrict__ P0,
    _Float16* __restrict__ P1, int nb0)
{
  __shared__ _Float16 As[128][136];
  int z = blockIdx.x;
  const _Float16* A; const _Float16* Wt; _Float16* P; int ldP, colBase, rowBase;
  if (z < nb0 * 5) {
    const int map0[5] = {0, 2, 4, 7, 9};
    int m = z / nb0, rb = z - m * nb0;
    A = f0h; rowBase = rb * 128;
    Wt = Wh + (size_t)map0[m] * 16384;
    P = P0; ldP = 640; colBase = m * 128;
  } else {
    z -= nb0 * 5;
    int nb1 = nb0 * 3;
    const int map1[7] = {1, 3, 5, 6, 8, 10, 11};
    int m = z / nb1, rb = z - m * nb1;
    A = f1h; rowBase = rb * 128;
    Wt = Wh + (size_t)map1[m] * 16384;
    P = P1; ldP = 896; colBase = m * 128;
  }
  MFMA_BODY(A, rowBase, Wt)
  #pragma unroll
  for (int mt = 0; mt < 8; ++mt) {
    #pragma unroll
    for (int ntl = 0; ntl < 2; ++ntl) {
      int col = colBase + (w * 2 + ntl) * 16 + r15;
      #pragma unroll
      for (int i = 0; i < 4; ++i) {
        int r = rowBase + mt * 16 + g * 4 + i;
        P[(size_t)r * ldP + col] = (_Float16)acc[mt][ntl][i];
      }
    }
  }
}

// ---------------------------------------------------------------- Wo MFMA + residual
__global__ __launch_bounds__(256) void k_wo_mfma(
    const _Float16* __restrict__ o0h, const _Float16* __restrict__ o1h,
    const _Float16* __restrict__ Who_l, const float* __restrict__ bo_l,
    float* __restrict__ f0, float* __restrict__ f1,
    _Float16* __restrict__ f0h, _Float16* __restrict__ f1h, int nb0)
{
  __shared__ _Float16 As[128][136];
  int z = blockIdx.x;
  const _Float16* A; const _Float16* Wt; const float* bias;
  float* F; _Float16* FH; int rowBase;
  if (z < nb0) {
    A = o0h; Wt = Who_l; bias = bo_l; F = f0; FH = f0h; rowBase = z * 128;
  } else {
    z -= nb0;
    A = o1h; Wt = Who_l + 16384; bias = bo_l + CC; F = f1; FH = f1h; rowBase = z * 128;
  }
  MFMA_BODY(A, rowBase, Wt)
  #pragma unroll
  for (int mt = 0; mt < 8; ++mt) {
    #pragma unroll
    for (int ntl = 0; ntl < 2; ++ntl) {
      int col = (w * 2 + ntl) * 16 + r15;
      float bv = bias[col];
      #pragma unroll
      for (int i = 0; i < 4; ++i) {
        int r = rowBase + mt * 16 + g * 4 + i;
        size_t p = (size_t)r * 128 + col;
        float val = F[p] + acc[mt][ntl][i] + bv;
        F[p] = val;
        FH[p] = (_Float16)val;
      }
    }
  }
}

// ---------------------------------------------------------------- attn v5
// 64 lanes per node: 32 channel-groups x 2 neighbor-halves (4 neighbors each),
// online softmax per half + shuffle merge. Rn precomputed. 4 nodes/block.
__global__ __launch_bounds__(256) void k_attn(
    const _Float16* __restrict__ P0, const _Float16* __restrict__ P1,
    const int* __restrict__ idx, const float* __restrict__ rhat,
    const _Float16* __restrict__ RnL,
    _Float16* __restrict__ o0h, _Float16* __restrict__ o1h,
    int nodeBase, int nbg)
{
  const int t = threadIdx.x;
  const int wv = t >> 6;            // node slot 0..3
  const int lane = t & 63;
  const int cl = lane & 31;         // channel group
  const int nh = lane >> 5;         // neighbor half
  const int z = blockIdx.x;
  const int bb = z % nbg;
  const int qbase = (z / nbg) * 4;
  const int nodeLocal = bb * NPTS + qbase + wv;
  const int node = nodeBase + nodeLocal;
  const int batchRow = bb * NPTS;

  __shared__ float rh_s[4][KNN][3];
  if (t < 96) {
    int nd = t / 24, e = t % 24;
    rh_s[nd][e / 3][e % 3] =
        rhat[((size_t)(nodeBase + bb * NPTS + qbase + nd)) * KNN * 3 + e];
  }
  __syncthreads();

  const int c0 = cl * 4;
  const int h = cl >> 2;
  const _Float16* p0n = P0 + (size_t)nodeLocal * 640 + c0;
  const _Float16* p1n = P1 + (size_t)nodeLocal * 2688 + c0;
  h4v q0v  = *(const h4v*)(p0n);
  h4v q1xv = *(const h4v*)(p1n);
  h4v q1yv = *(const h4v*)(p1n + 896);
  h4v q1zv = *(const h4v*)(p1n + 1792);

  const float inv_scale = 0.17677669529663687f;  // 1/sqrt(32)
  const int* idxp = idx + (size_t)node * KNN + nh * 4;
  int jls[4];
  #pragma unroll
  for (int k = 0; k < 4; ++k) jls[k] = batchRow + idxp[k];
  const _Float16* rnp = RnL + ((size_t)node * KNN + nh * 4) * 128 + h * 16;

  float m = -3.0e38f, ssum = 0.0f;
  float a0[4] = {}, ax[4] = {}, ay[4] = {}, az[4] = {};

  for (int k = 0; k < 4; ++k) {
    int kk = nh * 4 + k;
    int jl = jls[k];
    const _Float16* g0 = P0 + (size_t)jl * 640 + c0;
    const _Float16* g1 = P1 + (size_t)jl * 2688 + c0;
    float rx = rh_s[wv][kk][0], ry = rh_s[wv][kk][1], rz = rh_s[wv][kk][2];

    h4v G02 = *(const h4v*)(g0 + 128), G04 = *(const h4v*)(g0 + 256);
    h4v G07 = *(const h4v*)(g0 + 384), G09 = *(const h4v*)(g0 + 512);
    h4v G13x = *(const h4v*)(g1 + 128),  G13y = *(const h4v*)(g1 + 896 + 128),  G13z = *(const h4v*)(g1 + 1792 + 128);
    h4v G15x = *(const h4v*)(g1 + 256),  G15y = *(const h4v*)(g1 + 896 + 256),  G15z = *(const h4v*)(g1 + 1792 + 256);
    h4v G16x = *(const h4v*)(g1 + 384),  G16y = *(const h4v*)(g1 + 896 + 384),  G16z = *(const h4v*)(g1 + 1792 + 384);
    h4v G18x = *(const h4v*)(g1 + 512),  G18y = *(const h4v*)(g1 + 896 + 512),  G18z = *(const h4v*)(g1 + 1792 + 512);
    h4v G1Ax = *(const h4v*)(g1 + 640),  G1Ay = *(const h4v*)(g1 + 896 + 640),  G1Az = *(const h4v*)(g1 + 1792 + 640);
    h4v G1Bx = *(const h4v*)(g1 + 768),  G1By = *(const h4v*)(g1 + 896 + 768),  G1Bz = *(const h4v*)(g1 + 1792 + 768);

    half8 rv = *(const half8*)(rnp + (size_t)k * 128);
    h4v rv2 = *(const h4v*)(rnp + (size_t)k * 128 + 8);
    float r0 = (float)rv[0], r1 = (float)rv[1], r2 = (float)rv[2], r3 = (float)rv[3];
    float r4 = (float)rv[4], r5 = (float)rv[5], r6 = (float)rv[6], r7 = (float)rv[7];
    float r8 = (float)rv2[0], r9 = (float)rv2[1];

    float pl = 0.0f;
    float v0c[4], vxc[4], vyc[4], vzc[4];
    #pragma unroll
    for (int ci = 0; ci < 4; ++ci) {
      float g02 = (float)G02[ci], g04 = (float)G04[ci];
      float g07 = (float)G07[ci], g09 = (float)G09[ci];
      float g13x = (float)G13x[ci], g13y = (float)G13y[ci], g13z = (float)G13z[ci];
      float g15x = (float)G15x[ci], g15y = (float)G15y[ci], g15z = (float)G15z[ci];
      float g16x = (float)G16x[ci], g16y = (float)G16y[ci], g16z = (float)G16z[ci];
      float g18x = (float)G18x[ci], g18y = (float)G18y[ci], g18z = (float)G18z[ci];
      float g1ax = (float)G1Ax[ci], g1ay = (float)G1Ay[ci], g1az = (float)G1Az[ci];
      float g1bx = (float)G1Bx[ci], g1by = (float)G1By[ci], g1bz = (float)G1Bz[ci];

      float DP3 = g13x * rx + g13y * ry + g13z * rz;
      float DP6 = g16x * rx + g16y * ry + g16z * rz;
      float DP8 = g18x * rx + g18y * ry + g18z * rz;
      float DPB = g1bx * rx + g1by * ry + g1bz * rz;

      float k0  = g02 * r0 + DP3 * r1;
      float k1x = g04 * rx * r2 + g15x * r3 + (3.0f * rx * DP6 - g16x) * r4;
      float k1y = g04 * ry * r2 + g15y * r3 + (3.0f * ry * DP6 - g16y) * r4;
      float k1z = g04 * rz * r2 + g15z * r3 + (3.0f * rz * DP6 - g16z) * r4;
      v0c[ci] = g07 * r5 + DP8 * r6;
      vxc[ci] = g09 * rx * r7 + g1ax * r8 + (3.0f * rx * DPB - g1bx) * r9;
      vyc[ci] = g09 * ry * r7 + g1ay * r8 + (3.0f * ry * DPB - g1by) * r9;
      vzc[ci] = g09 * rz * r7 + g1az * r8 + (3.0f * rz * DPB - g1bz) * r9;

      pl += (float)q0v[ci] * k0 + (float)q1xv[ci] * k1x
          + (float)q1yv[ci] * k1y + (float)q1zv[ci] * k1z;
    }
    pl += __shfl_xor(pl, 1, 4);
    pl += __shfl_xor(pl, 2, 4);
    pl *= inv_scale;

    float mnew = fmaxf(m, pl);
    float scale = expf(m - mnew);
    float wgt = expf(pl - mnew);
    ssum = ssum * scale + wgt;
    #pragma unroll
    for (int ci = 0; ci < 4; ++ci) {
      a0[ci] = a0[ci] * scale + wgt * v0c[ci];
      ax[ci] = ax[ci] * scale + wgt * vxc[ci];
      ay[ci] = ay[ci] * scale + wgt * vyc[ci];
      az[ci] = az[ci] * scale + wgt * vzc[ci];
    }
    m = mnew;
  }

  // merge the two neighbor-halves (lane ^ 32)
  {
    float mo = __shfl_xor(m, 32, 64);
    float so = __shfl_xor(ssum, 32, 64);
    float mn = fmaxf(m, mo);
    float s_self = expf(m - mn);
    float s_oth  = expf(mo - mn);
    ssum = ssum * s_self + so * s_oth;
    #pragma unroll
    for (int ci = 0; ci < 4; ++ci) {
      float o0 = __shfl_xor(a0[ci], 32, 64);
      float ox = __shfl_xor(ax[ci], 32, 64);
      float oy = __shfl_xor(ay[ci], 32, 64);
      float oz = __shfl_xor(az[ci], 32, 64);
      a0[ci] = a0[ci] * s_self + o0 * s_oth;
      ax[ci] = ax[ci] * s_self + ox * s_oth;
      ay[ci] = ay[ci] * s_self + oy * s_oth;
      az[ci] = az[ci] * s_self + oz * s_oth;
    }
  }

  if (nh == 0) {
    float invs = 1.0f / ssum;
    h4v o;
    #pragma unroll
    for (int ci = 0; ci < 4; ++ci) o[ci] = (_Float16)(a0[ci] * invs);
    *(h4v*)(o0h + (size_t)nodeLocal * 128 + c0) = o;
    #pragma unroll
    for (int ci = 0; ci < 4; ++ci) o[ci] = (_Float16)(ax[ci] * invs);
    *(h4v*)(o1h + ((size_t)nodeLocal * 3 + 0) * 128 + c0) = o;
    #pragma unroll
    for (int ci = 0; ci < 4; ++ci) o[ci] = (_Float16)(ay[ci] * invs);
    *(h4v*)(o1h + ((size_t)nodeLocal * 3 + 1) * 128 + c0) = o;
    #pragma unroll
    for (int ci = 0; ci < 4; ++ci) o[ci] = (_Float16)(az[ci] * invs);
    *(h4v*)(o1h + ((size_t)nodeLocal * 3 + 2) * 128 + c0) = o;
  }
}

// ---------------------------------------------------------------- final out
__global__ __launch_bounds__(256) void k_out(
    const float* __restrict__ f1, const float* __restrict__ Wout,
    const float* __restrict__ bout, float* __restrict__ out)
{
  int i = blockIdx.x * 256 + threadIdx.x;
  int v = i % 3;
  const float* row = f1 + (size_t)i * CC;
  const float* w = Wout + v * CC;
  float acc = 0.0f;
  #pragma unroll
  for (int c = 0; c < CC; c += 4) {
    float4 fv = *(const float4*)&row[c];
    float4 wv = *(const float4*)&w[c];
    acc += fv.x * wv.x + fv.y * wv.y + fv.z * wv.z + fv.w * wv.w;
  }
  out[i] = acc + bout[v];
}

// ---------------------------------------------------------------- host
extern "C" void kernel_launch(void* const* d_in, const int* in_sizes, int n_in,
                              void* d_out, int out_size, void* d_ws, size_t ws_size,
                              hipStream_t stream) {
  const float* x    = (const float*)d_in[0];
  const float* t    = (const float*)d_in[2];
  const float* Wt1  = (const float*)d_in[3];
  const float* bt1  = (const float*)d_in[4];
  const float* Wt2  = (const float*)d_in[5];
  const float* bt2  = (const float*)d_in[6];
  const float* Win0 = (const float*)d_in[7];
  const float* bin0 = (const float*)d_in[8];
  const float* Win1 = (const float*)d_in[9];
  const float* Wqkv = (const float*)d_in[10];
  const float* Wr1  = (const float*)d_in[11];
  const float* br1  = (const float*)d_in[12];
  const float* Wr2  = (const float*)d_in[13];
  const float* br2  = (const float*)d_in[14];
  const float* Wo   = (const float*)d_in[15];
  const float* bo   = (const float*)d_in[16];
  const float* Wout = (const float*)d_in[17];
  const float* bout = (const float*)d_in[18];
  float* out = (float*)d_out;

  char* wsb = (char*)d_ws;
  size_t off = 0;
  auto alloc = [&](size_t bytes) -> void* {
    void* p = wsb + off;
    off = (off + bytes + 255) & ~(size_t)255;
    return p;
  };
  const int totalNodes = NBATCH * NPTS;  // 8192
  float* pre0 = (float*)alloc((size_t)NBATCH * CC * 4);
  float* f0   = (float*)alloc((size_t)totalNodes * CC * 4);
  float* f1   = (float*)alloc((size_t)totalNodes * 3 * CC * 4);
  _Float16* f0h = (_Float16*)alloc((size_t)totalNodes * CC * 2);
  _Float16* f1h = (_Float16*)alloc((size_t)totalNodes * 3 * CC * 2);
  _Float16* Whq = (_Float16*)alloc((size_t)NL * 12 * CC * HD_ * 2);
  _Float16* Who = (_Float16*)alloc((size_t)NL * 2 * CC * HD_ * 2);
  int*   idx  = (int*)alloc((size_t)totalNodes * KNN * 4);
  float* rhat = (float*)alloc((size_t)totalNodes * KNN * 3 * 4);
  float* rl   = (float*)alloc((size_t)totalNodes * KNN * 4);
  _Float16* Rn = (_Float16*)alloc((size_t)NL * totalNodes * KNN * 128 * 2);
  size_t fixedBytes = off;
  size_t perBatch = (size_t)NPTS * ((640 + 2688) * 2 + (128 + 384) * 2);
  int nbg = 8;
  while (nbg > 1 && fixedBytes + (size_t)nbg * perBatch + 8192 > ws_size) nbg >>= 1;
  _Float16* P0  = (_Float16*)alloc((size_t)nbg * NPTS * 640 * 2);
  _Float16* P1  = (_Float16*)alloc((size_t)nbg * NPTS * 2688 * 2);
  _Float16* o0h = (_Float16*)alloc((size_t)nbg * NPTS * 128 * 2);
  _Float16* o1h = (_Float16*)alloc((size_t)nbg * NPTS * 384 * 2);

  k_temb<<<NBATCH, 128, 0, stream>>>(t, Wt1, bt1, Wt2, bt2, Win0, bin0, pre0);
  k_init<<<totalNodes / 2, 256, 0, stream>>>(x, Win0, Win1, pre0, f0, f1, f0h, f1h);
  k_knn<<<NBATCH * 32, 256, 0, stream>>>(x, idx, rhat, rl);
  k_wconv<<<56, 256, 0, stream>>>(Wqkv, Wo, Whq, Who);
  k_rn<<<dim3(totalNodes * KNN / 64, NL), 256, 0, stream>>>(rl, Wr1, br1, Wr2, br2, Rn);

  for (int g = 0; g < NBATCH / nbg; ++g) {
    int nodeBase = g * nbg * NPTS;
    int nodes = nbg * NPTS;
    int nb0 = nodes / 128;
    for (int l = 0; l < NL; ++l) {
      k_proj_mfma<<<nb0 * 26, 256, 0, stream>>>(
          f0h + (size_t)nodeBase * CC, f1h + (size_t)nodeBase * 3 * CC,
          Whq + (size_t)l * 12 * CC * HD_, P0, P1, nb0);
      k_attn<<<nodes / 4, 256, 0, stream>>>(
          P0, P1, idx, rhat, Rn + (size_t)l * totalNodes * KNN * 128,
          o0h, o1h, nodeBase, nbg);
      k_wo_mfma<<<nb0 * 4, 256, 0, stream>>>(
          o0h, o1h, Who + (size_t)l * 2 * CC * HD_, bo + (size_t)(l * 2) * CC,
          f0 + (size_t)nodeBase * CC, f1 + (size_t)nodeBase * 3 * CC,
          f0h + (size_t)nodeBase * CC, f1h + (size_t)nodeBase * 3 * CC, nb0);
    }
  }
  k_out<<<(totalNodes * 3) / 256, 256, 0, stream>>>(f1, Wout, bout, out);
}

// Round 10
// 375.085 us; speedup vs baseline: 1.4462x; 1.1112x over previous
//
#include <hip/hip_runtime.h>
#include <math.h>

#define NBATCH 8
#define NPTS   1024
#define KNN    8
#define CC     128
#define HD_    128
#define TED_   128
#define TEC_   64
#define RH     32
#define NL     4

typedef _Float16 half8 __attribute__((ext_vector_type(8)));
typedef _Float16 h4v  __attribute__((ext_vector_type(4)));
typedef float f32x4 __attribute__((ext_vector_type(4)));

// ---------------------------------------------------------------- temb
__global__ __launch_bounds__(128) void k_temb(
    const float* __restrict__ t, const float* __restrict__ Wt1,
    const float* __restrict__ bt1, const float* __restrict__ Wt2,
    const float* __restrict__ bt2, const float* __restrict__ Win0,
    const float* __restrict__ bin0, float* __restrict__ pre0)
{
  int b = blockIdx.x;
  int tid = threadIdx.x;
  __shared__ float e128[TED_];
  __shared__ float h1[TED_];
  __shared__ float te[TEC_];
  float tv = t[b];
  if (tid < 64) {
    float fr = expf((-9.210340371976184f * (float)tid) * 0.015625f);
    float em = tv * fr;
    e128[tid]      = sinf(em);
    e128[tid + 64] = cosf(em);
  }
  __syncthreads();
  {
    float acc = bt1[tid];
    for (int i = 0; i < TED_; ++i) acc += e128[i] * Wt1[i * TED_ + tid];
    h1[tid] = acc / (1.0f + expf(-acc));
  }
  __syncthreads();
  if (tid < TEC_) {
    float acc = bt2[tid];
    for (int j = 0; j < TED_; ++j) acc += h1[j] * Wt2[j * TEC_ + tid];
    te[tid] = acc;
  }
  __syncthreads();
  {
    float acc = bin0[tid];
    for (int i = 0; i < TEC_; ++i) acc += te[i] * Win0[i * CC + tid];
    pre0[b * CC + tid] = acc;
  }
}

// ---------------------------------------------------------------- init f0/f1 (+fp16 copies)
__global__ __launch_bounds__(256) void k_init(
    const float* __restrict__ x, const float* __restrict__ Win0,
    const float* __restrict__ Win1, const float* __restrict__ pre0,
    float* __restrict__ f0, float* __restrict__ f1,
    _Float16* __restrict__ f0h, _Float16* __restrict__ f1h)
{
  int node = blockIdx.x * 2 + (threadIdx.x >> 7);
  int c = threadIdx.x & 127;
  int b = node >> 10;
  float x0 = x[node * 3 + 0], x1 = x[node * 3 + 1], x2 = x[node * 3 + 2];
  float acc = pre0[b * CC + c]
            + x0 * Win0[(TEC_ + 0) * CC + c]
            + x1 * Win0[(TEC_ + 1) * CC + c]
            + x2 * Win0[(TEC_ + 2) * CC + c];
  f0[(size_t)node * CC + c] = acc;
  f0h[(size_t)node * CC + c] = (_Float16)acc;
  float w1 = Win1[c];
  float v0 = x0 * w1, v1 = x1 * w1, v2 = x2 * w1;
  f1[((size_t)node * 3 + 0) * CC + c] = v0;
  f1[((size_t)node * 3 + 1) * CC + c] = v1;
  f1[((size_t)node * 3 + 2) * CC + c] = v2;
  f1h[((size_t)node * 3 + 0) * CC + c] = (_Float16)v0;
  f1h[((size_t)node * 3 + 1) * CC + c] = (_Float16)v1;
  f1h[((size_t)node * 3 + 2) * CC + c] = (_Float16)v2;
}

// ---------------------------------------------------------------- knn v4
// 64 lanes per query x 16 candidates each; full-wave extract-min merge.
// 4 queries per 256-thread block -> 2048 blocks (100% wave-slot ceiling).
__global__ __launch_bounds__(256) void k_knn(
    const float* __restrict__ x, int* __restrict__ idx,
    float* __restrict__ rhat, float* __restrict__ rl)
{
  const int b    = blockIdx.x >> 8;     // 256 blocks per batch
  const int tile = blockIdx.x & 255;    // 4 queries per block
  const int tid  = threadIdx.x;
  const int qg   = tid >> 6;            // query = wave
  const int sub  = tid & 63;            // scan slice

  __shared__ float xsx[NPTS], xsy[NPTS], xsz[NPTS];

  for (int i = tid; i < NPTS; i += 256) {
    const float* xp = x + ((size_t)b * NPTS + i) * 3;
    xsx[i] = xp[0]; xsy[i] = xp[1]; xsz[i] = xp[2];
  }
  __syncthreads();

  const int n = tile * 4 + qg;
  const float qx = xsx[n], qy = xsy[n], qz = xsz[n];

  unsigned long long bd[KNN];
  #pragma unroll
  for (int k = 0; k < KNN; ++k) bd[k] = ~0ull;

  const int j0 = sub * 16;
  #pragma unroll
  for (int it = 0; it < 16; ++it) {
    int j = j0 + ((it + sub) & 15);     // bank stagger
    float dx = qx - xsx[j];
    float dy = qy - xsy[j];
    float dz = qz - xsz[j];
    float s = __fadd_rn(__fadd_rn(__fmul_rn(dx, dx), __fmul_rn(dy, dy)),
                        __fmul_rn(dz, dz));
    if (j == n) s = 1.0e9f;
    unsigned long long key =
        ((unsigned long long)__float_as_uint(s) << 32) | (unsigned int)j;
    if (key < bd[KNN - 1]) {
      bd[KNN - 1] = key;
      #pragma unroll
      for (int q = KNN - 1; q > 0; --q) {
        if (bd[q] < bd[q - 1]) {
          unsigned long long tmp = bd[q]; bd[q] = bd[q - 1]; bd[q - 1] = tmp;
        }
      }
    }
  }

  // 8 rounds of full-wave extract-min (keys unique -> exactly one pop/round)
  unsigned long long res[KNN];
  #pragma unroll
  for (int r = 0; r < KNN; ++r) {
    unsigned long long m = bd[0];
    #pragma unroll
    for (int mk = 1; mk < 64; mk <<= 1) {
      unsigned long long o = (unsigned long long)__shfl_xor((long long)m, mk, 64);
      m = (o < m) ? o : m;
    }
    if (bd[0] == m) {
      #pragma unroll
      for (int q = 0; q < KNN - 1; ++q) bd[q] = bd[q + 1];
      bd[KNN - 1] = ~0ull;
    }
    res[r] = m;
  }

  if (sub < KNN) {
    unsigned long long key = res[0];
    #pragma unroll
    for (int r = 1; r < KNN; ++r) if (sub == r) key = res[r];
    int j = (int)(key & 0xffffffffu);
    size_t base = ((size_t)b * NPTS + n) * KNN + sub;
    idx[base] = j;
    float rx = xsx[j] - qx;
    float ry = xsy[j] - qy;
    float rz = xsz[j] - qz;
    float rr2 = rx * rx + ry * ry + rz * rz + 1e-8f;
    float r = sqrtf(rr2);
    rl[base] = r;
    rhat[base * 3 + 0] = rx / r;
    rhat[base * 3 + 1] = ry / r;
    rhat[base * 3 + 2] = rz / r;
  }
}

// ---------------------------------------------------------------- Rn precompute (MFMA GEMM)
__global__ __launch_bounds__(256) void k_rn(
    const float* __restrict__ rl, const float* __restrict__ Wr1,
    const float* __restrict__ br1, const float* __restrict__ Wr2,
    const float* __restrict__ br2, _Float16* __restrict__ Rn)
{
  const int l = blockIdx.y;
  const int e0 = blockIdx.x * 64;
  const int t = threadIdx.x;
  __shared__ _Float16 hid[64][48];
  __shared__ _Float16 wt[80][48];
  __shared__ _Float16 rn_lds[64][128];

  {
    uint4 zz = {0, 0, 0, 0};
    #pragma unroll
    for (int u = 0; u < 4; ++u)
      *(uint4*)((char*)rn_lds + (u * 256 + t) * 16) = zz;
  }
  {
    const float* wr2 = Wr2 + l * RH * 80;
    for (int i = t; i < 2560; i += 256) {
      int n = i >> 5, k = i & 31;
      wt[n][k] = (_Float16)wr2[k * 80 + n];
    }
  }
  {
    const float* wr1 = Wr1 + l * RH;
    const float* wb1 = br1 + l * RH;
    int e = t >> 2, i0 = (t & 3) * 8;
    float rv = rl[e0 + e];
    #pragma unroll
    for (int q = 0; q < 8; ++q) {
      int i = i0 + q;
      float zv = rv * wr1[i] + wb1[i];
      hid[e][i] = (_Float16)(zv / (1.0f + expf(-zv)));
    }
  }
  __syncthreads();

  {
    const int lane = t & 63;
    const int w = t >> 6;
    const int r15 = lane & 15;
    const int g = lane >> 4;
    half8 af = *(const half8*)&hid[w * 16 + r15][g * 8];
    const float* wb2 = br2 + l * 80;
    #pragma unroll
    for (int nt = 0; nt < 5; ++nt) {
      half8 bf = *(const half8*)&wt[nt * 16 + r15][g * 8];
      f32x4 acc = {};
      acc = __builtin_amdgcn_mfma_f32_16x16x32_f16(af, bf, acc, 0, 0, 0);
      int col = nt * 16 + r15;
      int hh = col / 10, j = col - hh * 10;
      float bv = wb2[col];
      #pragma unroll
      for (int i = 0; i < 4; ++i) {
        int e = w * 16 + g * 4 + i;
        rn_lds[e][hh * 16 + j] = (_Float16)(acc[i] + bv);
      }
    }
  }
  __syncthreads();
  _Float16* dst = Rn + ((size_t)l * 65536 + e0) * 128;
  #pragma unroll
  for (int u = 0; u < 4; ++u) {
    int i = u * 256 + t;
    *(uint4*)(dst + i * 8) = *(const uint4*)((const char*)rn_lds + i * 16);
  }
}

// ---------------------------------------------------------------- W convert+transpose (once)
__global__ __launch_bounds__(256) void k_wconv(
    const float* __restrict__ Wqkv, const float* __restrict__ Wo,
    _Float16* __restrict__ Whq, _Float16* __restrict__ Who)
{
  __shared__ _Float16 T[128][136];
  int m = blockIdx.x;
  const float* src; _Float16* dst;
  if (m < 48) { src = Wqkv + (size_t)m * 16384; dst = Whq + (size_t)m * 16384; }
  else { src = Wo + (size_t)(m - 48) * 16384; dst = Who + (size_t)(m - 48) * 16384; }
  int tid = threadIdx.x;
  for (int i = tid; i < 16384; i += 256) {
    int k = i >> 7, n = i & 127;
    T[n][k] = (_Float16)src[i];
  }
  __syncthreads();
  for (int i = tid; i < 16384; i += 256) {
    int n = i >> 7, k = i & 127;
    dst[i] = T[n][k];
  }
}

// ---------------------------------------------------------------- MFMA tile body (128x128x128)
#define MFMA_BODY(A_, ROWBASE_, WT_)                                          \
  const int tid  = threadIdx.x;                                               \
  const int lane = tid & 63;                                                  \
  const int w    = tid >> 6;                                                  \
  const int r15  = lane & 15;                                                 \
  const int g    = lane >> 4;                                                 \
  half8 bf[2][4];                                                             \
  _Pragma("unroll")                                                           \
  for (int ntl = 0; ntl < 2; ++ntl) {                                         \
    int n = (w * 2 + ntl) * 16 + r15;                                         \
    const _Float16* wp = (WT_) + (size_t)n * 128 + g * 8;                     \
    _Pragma("unroll")                                                         \
    for (int ks = 0; ks < 4; ++ks)                                            \
      bf[ntl][ks] = *(const half8*)(wp + ks * 32);                            \
  }                                                                           \
  {                                                                           \
    int r = tid >> 1;                                                         \
    const _Float16* src = (A_) + (size_t)((ROWBASE_) + r) * 128;              \
    int c0 = (tid & 1) * 8;                                                   \
    _Pragma("unroll")                                                         \
    for (int q = 0; q < 8; ++q) {                                             \
      int c = c0 + q;                                                         \
      *(uint4*)&As[r][c * 8] = *(const uint4*)(src + c * 8);                  \
    }                                                                         \
  }                                                                           \
  __syncthreads();                                                            \
  f32x4 acc[8][2] = {};                                                       \
  _Pragma("unroll")                                                           \
  for (int ks = 0; ks < 4; ++ks) {                                            \
    half8 a[8];                                                               \
    _Pragma("unroll")                                                         \
    for (int mt = 0; mt < 8; ++mt)                                            \
      a[mt] = *(const half8*)&As[mt * 16 + r15][ks * 32 + g * 8];             \
    _Pragma("unroll")                                                         \
    for (int mt = 0; mt < 8; ++mt) {                                          \
      acc[mt][0] = __builtin_amdgcn_mfma_f32_16x16x32_f16(a[mt], bf[0][ks], acc[mt][0], 0, 0, 0); \
      acc[mt][1] = __builtin_amdgcn_mfma_f32_16x16x32_f16(a[mt], bf[1][ks], acc[mt][1], 0, 0, 0); \
    }                                                                         \
  }

// ---------------------------------------------------------------- proj MFMA
__global__ __launch_bounds__(256) void k_proj_mfma(
    const _Float16* __restrict__ f0h, const _Float16* __restrict__ f1h,
    const _Float16* __restrict__ Wh, _Float16* __restrict__ P0,
    _Float16* __restrict__ P1, int nb0)
{
  __shared__ _Float16 As[128][136];
  int z = blockIdx.x;
  const _Float16* A; const _Float16* Wt; _Float16* P; int ldP, colBase, rowBase;
  if (z < nb0 * 5) {
    const int map0[5] = {0, 2, 4, 7, 9};
    int m = z / nb0, rb = z - m * nb0;
    A = f0h; rowBase = rb * 128;
    Wt = Wh + (size_t)map0[m] * 16384;
    P = P0; ldP = 640; colBase = m * 128;
  } else {
    z -= nb0 * 5;
    int nb1 = nb0 * 3;
    const int map1[7] = {1, 3, 5, 6, 8, 10, 11};
    int m = z / nb1, rb = z - m * nb1;
    A = f1h; rowBase = rb * 128;
    Wt = Wh + (size_t)map1[m] * 16384;
    P = P1; ldP = 896; colBase = m * 128;
  }
  MFMA_BODY(A, rowBase, Wt)
  #pragma unroll
  for (int mt = 0; mt < 8; ++mt) {
    #pragma unroll
    for (int ntl = 0; ntl < 2; ++ntl) {
      int col = colBase + (w * 2 + ntl) * 16 + r15;
      #pragma unroll
      for (int i = 0; i < 4; ++i) {
        int r = rowBase + mt * 16 + g * 4 + i;
        P[(size_t)r * ldP + col] = (_Float16)acc[mt][ntl][i];
      }
    }
  }
}

// ---------------------------------------------------------------- Wo MFMA + residual
__global__ __launch_bounds__(256) void k_wo_mfma(
    const _Float16* __restrict__ o0h, const _Float16* __restrict__ o1h,
    const _Float16* __restrict__ Who_l, const float* __restrict__ bo_l,
    float* __restrict__ f0, float* __restrict__ f1,
    _Float16* __restrict__ f0h, _Float16* __restrict__ f1h, int nb0)
{
  __shared__ _Float16 As[128][136];
  int z = blockIdx.x;
  const _Float16* A; const _Float16* Wt; const float* bias;
  float* F; _Float16* FH; int rowBase;
  if (z < nb0) {
    A = o0h; Wt = Who_l; bias = bo_l; F = f0; FH = f0h; rowBase = z * 128;
  } else {
    z -= nb0;
    A = o1h; Wt = Who_l + 16384; bias = bo_l + CC; F = f1; FH = f1h; rowBase = z * 128;
  }
  MFMA_BODY(A, rowBase, Wt)
  #pragma unroll
  for (int mt = 0; mt < 8; ++mt) {
    #pragma unroll
    for (int ntl = 0; ntl < 2; ++ntl) {
      int col = (w * 2 + ntl) * 16 + r15;
      float bv = bias[col];
      #pragma unroll
      for (int i = 0; i < 4; ++i) {
        int r = rowBase + mt * 16 + g * 4 + i;
        size_t p = (size_t)r * 128 + col;
        float val = F[p] + acc[mt][ntl][i] + bv;
        F[p] = val;
        FH[p] = (_Float16)val;
      }
    }
  }
}

// ---------------------------------------------------------------- attn v6
// v5 structure (32 ch-groups x 2 neighbor-halves) with K-phase / V-phase
// register split to cut peak VGPR liveness.
__global__ __launch_bounds__(256) void k_attn(
    const _Float16* __restrict__ P0, const _Float16* __restrict__ P1,
    const int* __restrict__ idx, const float* __restrict__ rhat,
    const _Float16* __restrict__ RnL,
    _Float16* __restrict__ o0h, _Float16* __restrict__ o1h,
    int nodeBase, int nbg)
{
  const int t = threadIdx.x;
  const int wv = t >> 6;
  const int lane = t & 63;
  const int cl = lane & 31;
  const int nh = lane >> 5;
  const int z = blockIdx.x;
  const int bb = z % nbg;
  const int qbase = (z / nbg) * 4;
  const int nodeLocal = bb * NPTS + qbase + wv;
  const int node = nodeBase + nodeLocal;
  const int batchRow = bb * NPTS;

  __shared__ float rh_s[4][KNN][3];
  if (t < 96) {
    int nd = t / 24, e = t % 24;
    rh_s[nd][e / 3][e % 3] =
        rhat[((size_t)(nodeBase + bb * NPTS + qbase + nd)) * KNN * 3 + e];
  }
  __syncthreads();

  const int c0 = cl * 4;
  const int h = cl >> 2;
  const _Float16* p0n = P0 + (size_t)nodeLocal * 640 + c0;
  const _Float16* p1n = P1 + (size_t)nodeLocal * 2688 + c0;
  h4v q0v  = *(const h4v*)(p0n);
  h4v q1xv = *(const h4v*)(p1n);
  h4v q1yv = *(const h4v*)(p1n + 896);
  h4v q1zv = *(const h4v*)(p1n + 1792);

  const float inv_scale = 0.17677669529663687f;  // 1/sqrt(32)
  const int* idxp = idx + (size_t)node * KNN + nh * 4;
  int jls[4];
  #pragma unroll
  for (int k = 0; k < 4; ++k) jls[k] = batchRow + idxp[k];
  const _Float16* rnp = RnL + ((size_t)node * KNN + nh * 4) * 128 + h * 16;

  float m = -3.0e38f, ssum = 0.0f;
  float a0[4] = {}, ax[4] = {}, ay[4] = {}, az[4] = {};

  for (int k = 0; k < 4; ++k) {
    int kk = nh * 4 + k;
    int jl = jls[k];
    const _Float16* g0 = P0 + (size_t)jl * 640 + c0;
    const _Float16* g1 = P1 + (size_t)jl * 2688 + c0;
    float rx = rh_s[wv][kk][0], ry = rh_s[wv][kk][1], rz = rh_s[wv][kk][2];

    half8 rv = *(const half8*)(rnp + (size_t)k * 128);
    h4v rv2 = *(const h4v*)(rnp + (size_t)k * 128 + 8);
    float r0 = (float)rv[0], r1 = (float)rv[1], r2 = (float)rv[2], r3 = (float)rv[3];
    float r4 = (float)rv[4], r5 = (float)rv[5], r6 = (float)rv[6], r7 = (float)rv[7];
    float r8 = (float)rv2[0], r9 = (float)rv2[1];

    // ---------------- K phase: logit only (k-side G rows)
    float pl = 0.0f;
    {
      h4v G02 = *(const h4v*)(g0 + 128), G04 = *(const h4v*)(g0 + 256);
      h4v G13x = *(const h4v*)(g1 + 128),  G13y = *(const h4v*)(g1 + 896 + 128),  G13z = *(const h4v*)(g1 + 1792 + 128);
      h4v G15x = *(const h4v*)(g1 + 256),  G15y = *(const h4v*)(g1 + 896 + 256),  G15z = *(const h4v*)(g1 + 1792 + 256);
      h4v G16x = *(const h4v*)(g1 + 384),  G16y = *(const h4v*)(g1 + 896 + 384),  G16z = *(const h4v*)(g1 + 1792 + 384);
      #pragma unroll
      for (int ci = 0; ci < 4; ++ci) {
        float g02 = (float)G02[ci], g04 = (float)G04[ci];
        float g13x = (float)G13x[ci], g13y = (float)G13y[ci], g13z = (float)G13z[ci];
        float g15x = (float)G15x[ci], g15y = (float)G15y[ci], g15z = (float)G15z[ci];
        float g16x = (float)G16x[ci], g16y = (float)G16y[ci], g16z = (float)G16z[ci];
        float DP3 = g13x * rx + g13y * ry + g13z * rz;
        float DP6 = g16x * rx + g16y * ry + g16z * rz;
        float k0  = g02 * r0 + DP3 * r1;
        float k1x = g04 * rx * r2 + g15x * r3 + (3.0f * rx * DP6 - g16x) * r4;
        float k1y = g04 * ry * r2 + g15y * r3 + (3.0f * ry * DP6 - g16y) * r4;
        float k1z = g04 * rz * r2 + g15z * r3 + (3.0f * rz * DP6 - g16z) * r4;
        pl += (float)q0v[ci] * k0 + (float)q1xv[ci] * k1x
            + (float)q1yv[ci] * k1y + (float)q1zv[ci] * k1z;
      }
    }
    pl += __shfl_xor(pl, 1, 4);
    pl += __shfl_xor(pl, 2, 4);
    pl *= inv_scale;

    float mnew = fmaxf(m, pl);
    float scale = expf(m - mnew);
    float wgt = expf(pl - mnew);
    ssum = ssum * scale + wgt;
    m = mnew;

    // ---------------- V phase: values (v-side G rows)
    {
      h4v G07 = *(const h4v*)(g0 + 384), G09 = *(const h4v*)(g0 + 512);
      h4v G18x = *(const h4v*)(g1 + 512),  G18y = *(const h4v*)(g1 + 896 + 512),  G18z = *(const h4v*)(g1 + 1792 + 512);
      h4v G1Ax = *(const h4v*)(g1 + 640),  G1Ay = *(const h4v*)(g1 + 896 + 640),  G1Az = *(const h4v*)(g1 + 1792 + 640);
      h4v G1Bx = *(const h4v*)(g1 + 768),  G1By = *(const h4v*)(g1 + 896 + 768),  G1Bz = *(const h4v*)(g1 + 1792 + 768);
      #pragma unroll
      for (int ci = 0; ci < 4; ++ci) {
        float g07 = (float)G07[ci], g09 = (float)G09[ci];
        float g18x = (float)G18x[ci], g18y = (float)G18y[ci], g18z = (float)G18z[ci];
        float g1ax = (float)G1Ax[ci], g1ay = (float)G1Ay[ci], g1az = (float)G1Az[ci];
        float g1bx = (float)G1Bx[ci], g1by = (float)G1By[ci], g1bz = (float)G1Bz[ci];
        float DP8 = g18x * rx + g18y * ry + g18z * rz;
        float DPB = g1bx * rx + g1by * ry + g1bz * rz;
        float v0  = g07 * r5 + DP8 * r6;
        float v1x = g09 * rx * r7 + g1ax * r8 + (3.0f * rx * DPB - g1bx) * r9;
        float v1y = g09 * ry * r7 + g1ay * r8 + (3.0f * ry * DPB - g1by) * r9;
        float v1z = g09 * rz * r7 + g1az * r8 + (3.0f * rz * DPB - g1bz) * r9;
        a0[ci] = a0[ci] * scale + wgt * v0;
        ax[ci] = ax[ci] * scale + wgt * v1x;
        ay[ci] = ay[ci] * scale + wgt * v1y;
        az[ci] = az[ci] * scale + wgt * v1z;
      }
    }
  }

  // merge the two neighbor-halves (lane ^ 32)
  {
    float mo = __shfl_xor(m, 32, 64);
    float so = __shfl_xor(ssum, 32, 64);
    float mn = fmaxf(m, mo);
    float s_self = expf(m - mn);
    float s_oth  = expf(mo - mn);
    ssum = ssum * s_self + so * s_oth;
    #pragma unroll
    for (int ci = 0; ci < 4; ++ci) {
      float o0 = __shfl_xor(a0[ci], 32, 64);
      float ox = __shfl_xor(ax[ci], 32, 64);
      float oy = __shfl_xor(ay[ci], 32, 64);
      float oz = __shfl_xor(az[ci], 32, 64);
      a0[ci] = a0[ci] * s_self + o0 * s_oth;
      ax[ci] = ax[ci] * s_self + ox * s_oth;
      ay[ci] = ay[ci] * s_self + oy * s_oth;
      az[ci] = az[ci] * s_self + oz * s_oth;
    }
  }

  if (nh == 0) {
    float invs = 1.0f / ssum;
    h4v o;
    #pragma unroll
    for (int ci = 0; ci < 4; ++ci) o[ci] = (_Float16)(a0[ci] * invs);
    *(h4v*)(o0h + (size_t)nodeLocal * 128 + c0) = o;
    #pragma unroll
    for (int ci = 0; ci < 4; ++ci) o[ci] = (_Float16)(ax[ci] * invs);
    *(h4v*)(o1h + ((size_t)nodeLocal * 3 + 0) * 128 + c0) = o;
    #pragma unroll
    for (int ci = 0; ci < 4; ++ci) o[ci] = (_Float16)(ay[ci] * invs);
    *(h4v*)(o1h + ((size_t)nodeLocal * 3 + 1) * 128 + c0) = o;
    #pragma unroll
    for (int ci = 0; ci < 4; ++ci) o[ci] = (_Float16)(az[ci] * invs);
    *(h4v*)(o1h + ((size_t)nodeLocal * 3 + 2) * 128 + c0) = o;
  }
}

// ---------------------------------------------------------------- final out
__global__ __launch_bounds__(256) void k_out(
    const float* __restrict__ f1, const float* __restrict__ Wout,
    const float* __restrict__ bout, float* __restrict__ out)
{
  int i = blockIdx.x * 256 + threadIdx.x;
  int v = i % 3;
  const float* row = f1 + (size_t)i * CC;
  const float* w = Wout + v * CC;
  float acc = 0.0f;
  #pragma unroll
  for (int c = 0; c < CC; c += 4) {
    float4 fv = *(const float4*)&row[c];
    float4 wv = *(const float4*)&w[c];
    acc += fv.x * wv.x + fv.y * wv.y + fv.z * wv.z + fv.w * wv.w;
  }
  out[i] = acc + bout[v];
}

// ---------------------------------------------------------------- host
extern "C" void kernel_launch(void* const* d_in, const int* in_sizes, int n_in,
                              void* d_out, int out_size, void* d_ws, size_t ws_size,
                              hipStream_t stream) {
  const float* x    = (const float*)d_in[0];
  const float* t    = (const float*)d_in[2];
  const float* Wt1  = (const float*)d_in[3];
  const float* bt1  = (const float*)d_in[4];
  const float* Wt2  = (const float*)d_in[5];
  const float* bt2  = (const float*)d_in[6];
  const float* Win0 = (const float*)d_in[7];
  const float* bin0 = (const float*)d_in[8];
  const float* Win1 = (const float*)d_in[9];
  const float* Wqkv = (const float*)d_in[10];
  const float* Wr1  = (const float*)d_in[11];
  const float* br1  = (const float*)d_in[12];
  const float* Wr2  = (const float*)d_in[13];
  const float* br2  = (const float*)d_in[14];
  const float* Wo   = (const float*)d_in[15];
  const float* bo   = (const float*)d_in[16];
  const float* Wout = (const float*)d_in[17];
  const float* bout = (const float*)d_in[18];
  float* out = (float*)d_out;

  char* wsb = (char*)d_ws;
  size_t off = 0;
  auto alloc = [&](size_t bytes) -> void* {
    void* p = wsb + off;
    off = (off + bytes + 255) & ~(size_t)255;
    return p;
  };
  const int totalNodes = NBATCH * NPTS;  // 8192
  float* pre0 = (float*)alloc((size_t)NBATCH * CC * 4);
  float* f0   = (float*)alloc((size_t)totalNodes * CC * 4);
  float* f1   = (float*)alloc((size_t)totalNodes * 3 * CC * 4);
  _Float16* f0h = (_Float16*)alloc((size_t)totalNodes * CC * 2);
  _Float16* f1h = (_Float16*)alloc((size_t)totalNodes * 3 * CC * 2);
  _Float16* Whq = (_Float16*)alloc((size_t)NL * 12 * CC * HD_ * 2);
  _Float16* Who = (_Float16*)alloc((size_t)NL * 2 * CC * HD_ * 2);
  int*   idx  = (int*)alloc((size_t)totalNodes * KNN * 4);
  float* rhat = (float*)alloc((size_t)totalNodes * KNN * 3 * 4);
  float* rl   = (float*)alloc((size_t)totalNodes * KNN * 4);
  _Float16* Rn = (_Float16*)alloc((size_t)NL * totalNodes * KNN * 128 * 2);
  size_t fixedBytes = off;
  size_t perBatch = (size_t)NPTS * ((640 + 2688) * 2 + (128 + 384) * 2);
  int nbg = 8;
  while (nbg > 1 && fixedBytes + (size_t)nbg * perBatch + 8192 > ws_size) nbg >>= 1;
  _Float16* P0  = (_Float16*)alloc((size_t)nbg * NPTS * 640 * 2);
  _Float16* P1  = (_Float16*)alloc((size_t)nbg * NPTS * 2688 * 2);
  _Float16* o0h = (_Float16*)alloc((size_t)nbg * NPTS * 128 * 2);
  _Float16* o1h = (_Float16*)alloc((size_t)nbg * NPTS * 384 * 2);

  k_temb<<<NBATCH, 128, 0, stream>>>(t, Wt1, bt1, Wt2, bt2, Win0, bin0, pre0);
  k_init<<<totalNodes / 2, 256, 0, stream>>>(x, Win0, Win1, pre0, f0, f1, f0h, f1h);
  k_knn<<<NBATCH * 256, 256, 0, stream>>>(x, idx, rhat, rl);
  k_wconv<<<56, 256, 0, stream>>>(Wqkv, Wo, Whq, Who);
  k_rn<<<dim3(totalNodes * KNN / 64, NL), 256, 0, stream>>>(rl, Wr1, br1, Wr2, br2, Rn);

  for (int g = 0; g < NBATCH / nbg; ++g) {
    int nodeBase = g * nbg * NPTS;
    int nodes = nbg * NPTS;
    int nb0 = nodes / 128;
    for (int l = 0; l < NL; ++l) {
      k_proj_mfma<<<nb0 * 26, 256, 0, stream>>>(
          f0h + (size_t)nodeBase * CC, f1h + (size_t)nodeBase * 3 * CC,
          Whq + (size_t)l * 12 * CC * HD_, P0, P1, nb0);
      k_attn<<<nodes / 4, 256, 0, stream>>>(
          P0, P1, idx, rhat, Rn + (size_t)l * totalNodes * KNN * 128,
          o0h, o1h, nodeBase, nbg);
      k_wo_mfma<<<nb0 * 4, 256, 0, stream>>>(
          o0h, o1h, Who + (size_t)l * 2 * CC * HD_, bo + (size_t)(l * 2) * CC,
          f0 + (size_t)nodeBase * CC, f1 + (size_t)nodeBase * 3 * CC,
          f0h + (size_t)nodeBase * CC, f1h + (size_t)nodeBase * 3 * CC, nb0);
    }
  }
  k_out<<<(totalNodes * 3) / 256, 256, 0, stream>>>(f1, Wout, bout, out);
}